// Round 1
// baseline (97561.682 us; speedup 1.0000x reference)
//
#include <hip/hip_runtime.h>
#include <math.h>

#define KP 8192
#define TSTEPS 4096
#define BLOCK 1024
#define PT 8                 // particles per thread = KP/BLOCK
#define NWAVES (BLOCK / 64)  // 16

// ---------------------------------------------------------------------------
// Transpose z [KP][TSTEPS] -> zT [TSTEPS][KP] so the scan kernel reads
// contiguous 32KB rows per timestep.
// ---------------------------------------------------------------------------
__global__ void transpose_k(const float* __restrict__ in, float* __restrict__ out) {
  __shared__ float tile[32][33];
  const int c0 = blockIdx.x * 32;  // T index base
  const int r0 = blockIdx.y * 32;  // K index base
  const int tx = threadIdx.x;      // 0..31
  const int ty = threadIdx.y;      // 0..7
#pragma unroll
  for (int i = 0; i < 32; i += 8)
    tile[ty + i][tx] = in[(size_t)(r0 + ty + i) * TSTEPS + c0 + tx];
  __syncthreads();
#pragma unroll
  for (int i = 0; i < 32; i += 8)
    out[(size_t)(c0 + ty + i) * KP + r0 + tx] = tile[tx][ty + i];
}

// ---------------------------------------------------------------------------
// Persistent single-workgroup SMC scan over T timesteps.
// Per step: log-weights -> block max -> exp + hierarchical prefix sum (cdf in
// LDS) -> lme accumulate -> branchless binary search per uniform -> gather w.
// ---------------------------------------------------------------------------
template <bool ZTRANS>
__global__ __launch_bounds__(BLOCK) void smc_scan(const float* __restrict__ x,
                                                  const float* __restrict__ w0,
                                                  const float* __restrict__ zsrc,
                                                  const float* __restrict__ u,
                                                  float* __restrict__ out) {
  extern __shared__ float sm[];
  float* w_s = sm;               // KP floats: current particles
  float* cdf_s = sm + KP;        // KP floats: unnormalized CDF
  float* xs = sm + 2 * KP;       // TSTEPS floats: observations
  float* red = xs + TSTEPS;      // NWAVES: wave partials
  float* red2 = red + NWAVES;    // NWAVES: scanned wave totals
  float* bc = red2 + NWAVES;     // 2: broadcast slots

  const int tid = threadIdx.x;
  const int lane = tid & 63;
  const int wid = tid >> 6;
  const int kbase = tid * PT;

  for (int i = tid; i < KP; i += BLOCK) w_s[i] = w0[i];
  for (int i = tid; i < TSTEPS; i += BLOCK) xs[i] = x[i];
  __syncthreads();

  // One-step-ahead prefetch registers.
  float zn[PT], un[PT];
  if (ZTRANS) {
    float4 a = *(const float4*)(zsrc + kbase);
    float4 b = *(const float4*)(zsrc + kbase + 4);
    zn[0] = a.x; zn[1] = a.y; zn[2] = a.z; zn[3] = a.w;
    zn[4] = b.x; zn[5] = b.y; zn[6] = b.z; zn[7] = b.w;
  } else {
#pragma unroll
    for (int j = 0; j < PT; ++j) zn[j] = zsrc[(size_t)(kbase + j) * TSTEPS];
  }
  {
    float4 a = *(const float4*)(u + kbase);
    float4 b = *(const float4*)(u + kbase + 4);
    un[0] = a.x; un[1] = a.y; un[2] = a.z; un[3] = a.w;
    un[4] = b.x; un[5] = b.y; un[6] = b.z; un[7] = b.w;
  }

  float acc = 0.f;

  for (int t = 0; t < TSTEPS; ++t) {
    float zv[PT], uv[PT];
#pragma unroll
    for (int j = 0; j < PT; ++j) { zv[j] = zn[j]; uv[j] = un[j]; }

    // Prefetch next step's z and u rows (hides HBM latency under compute).
    if (t + 1 < TSTEPS) {
      if (ZTRANS) {
        float4 a = *(const float4*)(zsrc + (size_t)(t + 1) * KP + kbase);
        float4 b = *(const float4*)(zsrc + (size_t)(t + 1) * KP + kbase + 4);
        zn[0] = a.x; zn[1] = a.y; zn[2] = a.z; zn[3] = a.w;
        zn[4] = b.x; zn[5] = b.y; zn[6] = b.z; zn[7] = b.w;
      } else {
#pragma unroll
        for (int j = 0; j < PT; ++j)
          zn[j] = zsrc[(size_t)(kbase + j) * TSTEPS + t + 1];
      }
      float4 a = *(const float4*)(u + (size_t)(t + 1) * KP + kbase);
      float4 b = *(const float4*)(u + (size_t)(t + 1) * KP + kbase + 4);
      un[0] = a.x; un[1] = a.y; un[2] = a.z; un[3] = a.w;
      un[4] = b.x; un[5] = b.y; un[6] = b.z; un[7] = b.w;
    }

    const float xt = xs[t];

    // Shifted log-weights: lw = -0.5*(z-w)^2 + x*z
    // (the per-k-constant -0.5*LOG2PI - 0.5*x^2 folds into the lme scalar;
    //  softmax/searchsorted are shift-invariant.)
    float lw[PT];
    float m8 = -3.4e38f;
#pragma unroll
    for (int j = 0; j < PT; ++j) {
      float d = zv[j] - w_s[kbase + j];
      lw[j] = fmaf(xt, zv[j], -0.5f * d * d);
      m8 = fmaxf(m8, lw[j]);
    }

    // Block max reduce.
#pragma unroll
    for (int m = 1; m <= 32; m <<= 1) m8 = fmaxf(m8, __shfl_xor(m8, m));
    if (lane == 0) red[wid] = m8;
    __syncthreads();
    if (wid == 0) {
      float v = (lane < NWAVES) ? red[lane] : -3.4e38f;
#pragma unroll
      for (int m = 1; m < NWAVES; m <<= 1) v = fmaxf(v, __shfl_xor(v, m));
      if (lane == 0) bc[0] = v;
    }
    __syncthreads();
    const float M = bc[0];

    // exp + thread-local inclusive scan.
    float s[PT];
    float run = 0.f;
#pragma unroll
    for (int j = 0; j < PT; ++j) {
      run += __expf(lw[j] - M);
      s[j] = run;
    }
    // Wave inclusive scan of per-thread totals.
    float wincl = run;
#pragma unroll
    for (int d = 1; d < 64; d <<= 1) {
      float n = __shfl_up(wincl, d);
      if (lane >= d) wincl += n;
    }
    if (lane == 63) red[wid] = wincl;
    const float wexcl = wincl - run;
    __syncthreads();
    if (wid == 0 && lane < NWAVES) {
      float v = red[lane];
#pragma unroll
      for (int d = 1; d < NWAVES; d <<= 1) {
        float n = __shfl_up(v, d);
        if (lane >= d) v += n;
      }
      red2[lane] = v;
    }
    __syncthreads();
    const float base = (wid ? red2[wid - 1] : 0.f) + wexcl;
    const float total = red2[NWAVES - 1];

    // Write unnormalized CDF.
#pragma unroll
    for (int j = 0; j < PT; ++j) cdf_s[kbase + j] = base + s[j];

    // lme accumulate (thread 0 only; constant shift re-added here).
    if (tid == 0)
      acc += M + __logf(total) - 9.0109133472792886f   // log(K)
             - 0.5f * (1.8378770664093453f + xt * xt); // LOG2PI + x^2 shift
    __syncthreads();

    // Branchless lower_bound: pos = first i with cdf[i] >= u*total,
    // naturally clipped to KP-1 (matches reference clip).
    int pos[PT];
    float tgt[PT];
#pragma unroll
    for (int j = 0; j < PT; ++j) {
      pos[j] = 0;
      tgt[j] = uv[j] * total;
    }
#pragma unroll
    for (int stp = KP >> 1; stp >= 1; stp >>= 1) {
#pragma unroll
      for (int j = 0; j < PT; ++j) {
        float c = cdf_s[pos[j] + stp - 1];
        if (c < tgt[j]) pos[j] += stp;
      }
    }

    // Resample gather (read all before overwrite).
    float nw[PT];
#pragma unroll
    for (int j = 0; j < PT; ++j) nw[j] = w_s[pos[j]];
    __syncthreads();
#pragma unroll
    for (int j = 0; j < PT; ++j) w_s[kbase + j] = nw[j];
    __syncthreads();
  }

  if (tid == 0) out[0] = acc;
}

// ---------------------------------------------------------------------------
extern "C" void kernel_launch(void* const* d_in, const int* in_sizes, int n_in,
                              void* d_out, int out_size, void* d_ws, size_t ws_size,
                              hipStream_t stream) {
  const float* x = (const float*)d_in[0];   // [T]
  const float* w0 = (const float*)d_in[1];  // [K]
  const float* z = (const float*)d_in[2];   // [K,T]
  const float* u = (const float*)d_in[3];   // [T,K]
  float* out = (float*)d_out;

  const size_t zbytes = (size_t)KP * TSTEPS * sizeof(float);
  const size_t shmem = (size_t)(2 * KP + TSTEPS + 2 * NWAVES + 2) * sizeof(float);

  if (ws_size >= zbytes) {
    float* zT = (float*)d_ws;
    transpose_k<<<dim3(TSTEPS / 32, KP / 32), dim3(32, 8), 0, stream>>>(z, zT);
    smc_scan<true><<<1, BLOCK, shmem, stream>>>(x, w0, zT, u, out);
  } else {
    // Fallback: strided z reads (correct, slower) if workspace too small.
    smc_scan<false><<<1, BLOCK, shmem, stream>>>(x, w0, z, u, out);
  }
}

// Round 2
// 36531.818 us; speedup vs baseline: 2.6706x; 2.6706x over previous
//
#include <hip/hip_runtime.h>
#include <math.h>

#define KP 8192
#define TSTEPS 4096
#define BLOCK 1024
#define PT 8                 // particles per thread = KP/BLOCK
#define NWAVES (BLOCK / 64)  // 16

// Bank-conflict-avoiding swizzle for the CDF array.
//  - (i>>3): spreads per-thread stride-8 writes across banks (9t mod 32, gcd(9,32)=1)
//  - (i>>8): spreads power-of-2 binary-search probes (p = m*stp + stp-1) across banks
// Strictly increasing in i -> bijective. Max = 8191+1023+31 = 9245.
#define SW(i) ((i) + ((i) >> 3) + ((i) >> 8))
#define CDF_PAD 9248

// ---------------------------------------------------------------------------
// Transpose z [KP][TSTEPS] -> zT [TSTEPS][KP] so the scan kernel reads
// contiguous 32KB rows per timestep.
// ---------------------------------------------------------------------------
__global__ void transpose_k(const float* __restrict__ in, float* __restrict__ out) {
  __shared__ float tile[32][33];
  const int c0 = blockIdx.x * 32;  // T index base
  const int r0 = blockIdx.y * 32;  // K index base
  const int tx = threadIdx.x;      // 0..31
  const int ty = threadIdx.y;      // 0..7
#pragma unroll
  for (int i = 0; i < 32; i += 8)
    tile[ty + i][tx] = in[(size_t)(r0 + ty + i) * TSTEPS + c0 + tx];
  __syncthreads();
#pragma unroll
  for (int i = 0; i < 32; i += 8)
    out[(size_t)(c0 + ty + i) * KP + r0 + tx] = tile[tx][ty + i];
}

// ---------------------------------------------------------------------------
// Persistent single-workgroup SMC scan over T timesteps.
// ---------------------------------------------------------------------------
template <bool ZTRANS>
__global__ __launch_bounds__(BLOCK) void smc_scan(const float* __restrict__ x,
                                                  const float* __restrict__ w0,
                                                  const float* __restrict__ zsrc,
                                                  const float* __restrict__ u,
                                                  float* __restrict__ out) {
  extern __shared__ float sm[];
  float* w_s = sm;                 // KP: current particles (linear layout)
  float* cdf_s = sm + KP;          // CDF_PAD: swizzled unnormalized CDF
  float* xs = cdf_s + CDF_PAD;     // TSTEPS: observations
  float* red = xs + TSTEPS;        // NWAVES: wave partials
  float* red2 = red + NWAVES;      // NWAVES: scanned wave totals
  float* bc = red2 + NWAVES;       // 2: broadcast slots

  const int tid = threadIdx.x;
  const int lane = tid & 63;
  const int wid = tid >> 6;
  const int kbase = tid * PT;
  const int wbase = SW(kbase);     // swizzle is affine within each aligned 8-run

  for (int i = tid; i < KP; i += BLOCK) w_s[i] = w0[i];
  for (int i = tid; i < TSTEPS; i += BLOCK) xs[i] = x[i];
  __syncthreads();

  // One-step-ahead prefetch registers.
  float zn[PT], un[PT];
  if (ZTRANS) {
    float4 a = *(const float4*)(zsrc + kbase);
    float4 b = *(const float4*)(zsrc + kbase + 4);
    zn[0] = a.x; zn[1] = a.y; zn[2] = a.z; zn[3] = a.w;
    zn[4] = b.x; zn[5] = b.y; zn[6] = b.z; zn[7] = b.w;
  } else {
#pragma unroll
    for (int j = 0; j < PT; ++j) zn[j] = zsrc[(size_t)(kbase + j) * TSTEPS];
  }
  {
    float4 a = *(const float4*)(u + kbase);
    float4 b = *(const float4*)(u + kbase + 4);
    un[0] = a.x; un[1] = a.y; un[2] = a.z; un[3] = a.w;
    un[4] = b.x; un[5] = b.y; un[6] = b.z; un[7] = b.w;
  }

  float acc = 0.f;

  for (int t = 0; t < TSTEPS; ++t) {
    float zv[PT], uv[PT];
#pragma unroll
    for (int j = 0; j < PT; ++j) { zv[j] = zn[j]; uv[j] = un[j]; }

    // Prefetch next step's z and u rows (hides HBM latency under compute).
    if (t + 1 < TSTEPS) {
      if (ZTRANS) {
        float4 a = *(const float4*)(zsrc + (size_t)(t + 1) * KP + kbase);
        float4 b = *(const float4*)(zsrc + (size_t)(t + 1) * KP + kbase + 4);
        zn[0] = a.x; zn[1] = a.y; zn[2] = a.z; zn[3] = a.w;
        zn[4] = b.x; zn[5] = b.y; zn[6] = b.z; zn[7] = b.w;
      } else {
#pragma unroll
        for (int j = 0; j < PT; ++j)
          zn[j] = zsrc[(size_t)(kbase + j) * TSTEPS + t + 1];
      }
      float4 a = *(const float4*)(u + (size_t)(t + 1) * KP + kbase);
      float4 b = *(const float4*)(u + (size_t)(t + 1) * KP + kbase + 4);
      un[0] = a.x; un[1] = a.y; un[2] = a.z; un[3] = a.w;
      un[4] = b.x; un[5] = b.y; un[6] = b.z; un[7] = b.w;
    }

    const float xt = xs[t];

    // Load my 8 particles as two float4 (ds_read_b128, conflict-benign).
    float wv[PT];
    {
      float4 a = *(const float4*)(w_s + kbase);
      float4 b = *(const float4*)(w_s + kbase + 4);
      wv[0] = a.x; wv[1] = a.y; wv[2] = a.z; wv[3] = a.w;
      wv[4] = b.x; wv[5] = b.y; wv[6] = b.z; wv[7] = b.w;
    }

    // Shifted log-weights: lw = -0.5*(z-w)^2 + x*z
    // (per-k-constant -0.5*LOG2PI - 0.5*x^2 folds into the lme scalar.)
    float lw[PT];
    float m8 = -3.4e38f;
#pragma unroll
    for (int j = 0; j < PT; ++j) {
      float d = zv[j] - wv[j];
      lw[j] = fmaf(xt, zv[j], -0.5f * d * d);
      m8 = fmaxf(m8, lw[j]);
    }

    // Block max reduce.
#pragma unroll
    for (int m = 1; m <= 32; m <<= 1) m8 = fmaxf(m8, __shfl_xor(m8, m));
    if (lane == 0) red[wid] = m8;
    __syncthreads();
    if (wid == 0) {
      float v = (lane < NWAVES) ? red[lane] : -3.4e38f;
#pragma unroll
      for (int m = 1; m < NWAVES; m <<= 1) v = fmaxf(v, __shfl_xor(v, m));
      if (lane == 0) bc[0] = v;
    }
    __syncthreads();
    const float M = bc[0];

    // exp + thread-local inclusive scan.
    float s[PT];
    float run = 0.f;
#pragma unroll
    for (int j = 0; j < PT; ++j) {
      run += __expf(lw[j] - M);
      s[j] = run;
    }
    // Wave inclusive scan of per-thread totals.
    float wincl = run;
#pragma unroll
    for (int d = 1; d < 64; d <<= 1) {
      float n = __shfl_up(wincl, d);
      if (lane >= d) wincl += n;
    }
    if (lane == 63) red[wid] = wincl;
    const float wexcl = wincl - run;
    __syncthreads();
    if (wid == 0 && lane < NWAVES) {
      float v = red[lane];
#pragma unroll
      for (int d = 1; d < NWAVES; d <<= 1) {
        float n = __shfl_up(v, d);
        if (lane >= d) v += n;
      }
      red2[lane] = v;
    }
    __syncthreads();
    const float base = (wid ? red2[wid - 1] : 0.f) + wexcl;
    const float total = red2[NWAVES - 1];

    // Write unnormalized CDF at swizzled addresses (conflict-free: 9t mod 32).
#pragma unroll
    for (int j = 0; j < PT; ++j) cdf_s[wbase + j] = base + s[j];

    // lme accumulate (thread 0 only; constant shift re-added here).
    if (tid == 0)
      acc += M + __logf(total) - 9.0109133472792886f   // log(K)
             - 0.5f * (1.8378770664093453f + xt * xt); // LOG2PI + x^2 shift
    __syncthreads();

    // Branchless lower_bound on swizzled CDF: pos = first i with cdf[i] >= u*total,
    // naturally clipped to KP-1 (matches reference clip).
    int pos[PT];
    float tgt[PT];
#pragma unroll
    for (int j = 0; j < PT; ++j) {
      pos[j] = 0;
      tgt[j] = uv[j] * total;
    }
#pragma unroll
    for (int stp = KP >> 1; stp >= 1; stp >>= 1) {
#pragma unroll
      for (int j = 0; j < PT; ++j) {
        const int p = pos[j] | (stp - 1);   // pos is a multiple of 2*stp here
        const float c = cdf_s[SW(p)];
        if (c < tgt[j]) pos[j] = p + 1;     // == pos[j] + stp
      }
    }

    // Resample gather (read all before overwrite).
    float nw[PT];
#pragma unroll
    for (int j = 0; j < PT; ++j) nw[j] = w_s[pos[j]];
    __syncthreads();
    {
      float4 a, b;
      a.x = nw[0]; a.y = nw[1]; a.z = nw[2]; a.w = nw[3];
      b.x = nw[4]; b.y = nw[5]; b.z = nw[6]; b.w = nw[7];
      *(float4*)(w_s + kbase) = a;
      *(float4*)(w_s + kbase + 4) = b;
    }
    __syncthreads();
  }

  if (tid == 0) out[0] = acc;
}

// ---------------------------------------------------------------------------
extern "C" void kernel_launch(void* const* d_in, const int* in_sizes, int n_in,
                              void* d_out, int out_size, void* d_ws, size_t ws_size,
                              hipStream_t stream) {
  const float* x = (const float*)d_in[0];   // [T]
  const float* w0 = (const float*)d_in[1];  // [K]
  const float* z = (const float*)d_in[2];   // [K,T]
  const float* u = (const float*)d_in[3];   // [T,K]
  float* out = (float*)d_out;

  const size_t zbytes = (size_t)KP * TSTEPS * sizeof(float);
  const size_t shmem =
      (size_t)(KP + CDF_PAD + TSTEPS + 2 * NWAVES + 2) * sizeof(float);

  if (ws_size >= zbytes) {
    float* zT = (float*)d_ws;
    transpose_k<<<dim3(TSTEPS / 32, KP / 32), dim3(32, 8), 0, stream>>>(z, zT);
    smc_scan<true><<<1, BLOCK, shmem, stream>>>(x, w0, zT, u, out);
  } else {
    // Fallback: strided z reads (correct, slower) if workspace too small.
    smc_scan<false><<<1, BLOCK, shmem, stream>>>(x, w0, z, u, out);
  }
}

// Round 3
// 33813.513 us; speedup vs baseline: 2.8853x; 1.0804x over previous
//
#include <hip/hip_runtime.h>
#include <math.h>

#define KP 8192
#define TSTEPS 4096
#define BLOCK 1024
#define PT 8                 // particles per thread = KP/BLOCK
#define NWAVES (BLOCK / 64)  // 16
#define NBUCK 8192           // bucket table size (avg occupancy 1)

// Bank-conflict-avoiding swizzle for the CDF array (stride-8 writes -> 9t mod 32).
#define SW(i) ((i) + ((i) >> 3) + ((i) >> 8))
#define CDF_PAD 9248

// ---------------------------------------------------------------------------
// Transpose z [KP][TSTEPS] -> zT [TSTEPS][KP].
// ---------------------------------------------------------------------------
__global__ void transpose_k(const float* __restrict__ in, float* __restrict__ out) {
  __shared__ float tile[32][33];
  const int c0 = blockIdx.x * 32;
  const int r0 = blockIdx.y * 32;
  const int tx = threadIdx.x;
  const int ty = threadIdx.y;
#pragma unroll
  for (int i = 0; i < 32; i += 8)
    tile[ty + i][tx] = in[(size_t)(r0 + ty + i) * TSTEPS + c0 + tx];
  __syncthreads();
#pragma unroll
  for (int i = 0; i < 32; i += 8)
    out[(size_t)(c0 + ty + i) * KP + r0 + tx] = tile[tx][ty + i];
}

// ---------------------------------------------------------------------------
// Persistent single-workgroup SMC scan.
// Per step: exp-weights -> hierarchical prefix sum -> cdf + bucket table ->
// O(1)-start forward search -> gather. No max-reduce (fp32 range suffices:
// w is only ever a permutation of w0, so |w|<~4.2, lw in [-60,+25]).
// ---------------------------------------------------------------------------
template <bool ZTRANS>
__global__ __launch_bounds__(BLOCK) void smc_scan(const float* __restrict__ x,
                                                  const float* __restrict__ w0,
                                                  const float* __restrict__ zsrc,
                                                  const float* __restrict__ u,
                                                  float* __restrict__ out) {
  extern __shared__ float sm[];
  float* w_s = sm;                  // KP: particle pool (linear)
  float* cdf_s = sm + KP;           // CDF_PAD: swizzled unnormalized CDF
  float* xs = cdf_s + CDF_PAD;      // TSTEPS: observations
  float* red = xs + TSTEPS;         // NWAVES: wave totals
  int* L_s = (int*)(red + NWAVES);  // NBUCK: bucket -> lower_bound index

  const int tid = threadIdx.x;
  const int lane = tid & 63;
  const int wid = tid >> 6;
  const int kbase = tid * PT;
  const int wbase = SW(kbase);  // swizzle affine within aligned 8-run

  for (int i = tid; i < KP; i += BLOCK) w_s[i] = w0[i];
  for (int i = tid; i < TSTEPS; i += BLOCK) xs[i] = x[i];
  for (int i = tid; i < NBUCK; i += BLOCK) L_s[i] = 0;  // belt (rebuilt each step)

  // Particles live in registers; w_s mirrors them for cross-thread gathers.
  float wv[PT];
  {
    float4 a = *(const float4*)(w0 + kbase);
    float4 b = *(const float4*)(w0 + kbase + 4);
    wv[0] = a.x; wv[1] = a.y; wv[2] = a.z; wv[3] = a.w;
    wv[4] = b.x; wv[5] = b.y; wv[6] = b.z; wv[7] = b.w;
  }
  __syncthreads();

  // One-step-ahead prefetch registers.
  float zn[PT], un[PT];
  if (ZTRANS) {
    float4 a = *(const float4*)(zsrc + kbase);
    float4 b = *(const float4*)(zsrc + kbase + 4);
    zn[0] = a.x; zn[1] = a.y; zn[2] = a.z; zn[3] = a.w;
    zn[4] = b.x; zn[5] = b.y; zn[6] = b.z; zn[7] = b.w;
  } else {
#pragma unroll
    for (int j = 0; j < PT; ++j) zn[j] = zsrc[(size_t)(kbase + j) * TSTEPS];
  }
  {
    float4 a = *(const float4*)(u + kbase);
    float4 b = *(const float4*)(u + kbase + 4);
    un[0] = a.x; un[1] = a.y; un[2] = a.z; un[3] = a.w;
    un[4] = b.x; un[5] = b.y; un[6] = b.z; un[7] = b.w;
  }

  float acc = 0.f;

  for (int t = 0; t < TSTEPS; ++t) {
    float zv[PT], uv[PT];
#pragma unroll
    for (int j = 0; j < PT; ++j) { zv[j] = zn[j]; uv[j] = un[j]; }

    if (t + 1 < TSTEPS) {
      if (ZTRANS) {
        float4 a = *(const float4*)(zsrc + (size_t)(t + 1) * KP + kbase);
        float4 b = *(const float4*)(zsrc + (size_t)(t + 1) * KP + kbase + 4);
        zn[0] = a.x; zn[1] = a.y; zn[2] = a.z; zn[3] = a.w;
        zn[4] = b.x; zn[5] = b.y; zn[6] = b.z; zn[7] = b.w;
      } else {
#pragma unroll
        for (int j = 0; j < PT; ++j)
          zn[j] = zsrc[(size_t)(kbase + j) * TSTEPS + t + 1];
      }
      float4 a = *(const float4*)(u + (size_t)(t + 1) * KP + kbase);
      float4 b = *(const float4*)(u + (size_t)(t + 1) * KP + kbase + 4);
      un[0] = a.x; un[1] = a.y; un[2] = a.z; un[3] = a.w;
      un[4] = b.x; un[5] = b.y; un[6] = b.z; un[7] = b.w;
    }

    const float xt = xs[t];

    // ---- A: shifted weights, exp (no max-sub), thread-local inclusive scan.
    float s[PT];
    float run = 0.f;
#pragma unroll
    for (int j = 0; j < PT; ++j) {
      float d = zv[j] - wv[j];
      float lw = fmaf(xt, zv[j], -0.5f * d * d);
      run += __expf(lw);
      s[j] = run;
    }
    // Wave inclusive scan of per-thread totals.
    float wincl = run;
#pragma unroll
    for (int d = 1; d < 64; d <<= 1) {
      float n = __shfl_up(wincl, d);
      if (lane >= d) wincl += n;
    }
    if (lane == 63) red[wid] = wincl;
    const float wexcl = wincl - run;
    __syncthreads();  // B1

    // ---- B: every wave redundantly scans the 16 wave totals (no 2nd barrier).
    float v = red[lane & 15];
#pragma unroll
    for (int d = 1; d < 16; d <<= 1) {
      float n = __shfl_up(v, d, 16);
      if ((lane & 15) >= d) v += n;
    }
    const float wpre = wid ? __shfl(v, wid - 1, 16) : 0.f;
    const float total = __shfl(v, 15, 16);
    const float base = wpre + wexcl;
    const float nbOverT = (float)NBUCK / total;

    // ---- C1: cdf values (single source of truth) + swizzled write.
    float cv[PT];
#pragma unroll
    for (int j = 0; j < PT; ++j) {
      cv[j] = base + s[j];
      cdf_s[wbase + j] = cv[j];
    }
    __syncthreads();  // B2

    // ---- C2: bucket table build. Particle i covers buckets
    // (floor(c_{i-1}*k), floor(c_i*k)]; consecutive boundaries use identical
    // stored FP values -> exact partition, no gaps, no duplicate writers.
    {
      const float cprev = (tid == 0) ? 0.f : cdf_s[SW(kbase - 1)];
      int flo = (int)(cprev * nbOverT);
#pragma unroll
      for (int j = 0; j < PT; ++j) {
        int fhi = (int)(cv[j] * nbOverT);
        if (fhi > NBUCK - 1) fhi = NBUCK - 1;
        if (kbase + j == KP - 1) fhi = NBUCK - 1;  // cover top buckets
        for (int b = flo + 1; b <= fhi; ++b) L_s[b] = kbase + j;
        flo = fhi;
      }
    }
    if (tid == 0)
      acc += __logf(total) - 9.0109133472792886f   // log(K)
             - 0.5f * (1.8378770664093453f + xt * xt);
    __syncthreads();  // B3

    // ---- D: O(1)-start searches. i0 = L[bucket(tgt)] is a proven lower
    // start (monotone FP mul); forward scan to exact clipped lower bound.
    int pos[PT];
    float tg[PT];
#pragma unroll
    for (int j = 0; j < PT; ++j) {
      tg[j] = uv[j] * total;
      int b = (int)(tg[j] * nbOverT);
      if (b > NBUCK - 1) b = NBUCK - 1;
      int i0 = L_s[b];
      i0 = i0 < 0 ? 0 : (i0 > KP - 1 ? KP - 1 : i0);
      pos[j] = i0;
    }
    bool ch = true;
    while (ch) {  // parallel rounds, ILP=8 hides ds_read latency
      ch = false;
#pragma unroll
      for (int j = 0; j < PT; ++j) {
        float c = cdf_s[SW(pos[j])];
        bool adv = (pos[j] < KP - 1) && (c < tg[j]);
        pos[j] += adv ? 1 : 0;
        ch |= adv;
      }
    }

    // ---- E: gather, publish, keep own slice in registers.
    float nw[PT];
#pragma unroll
    for (int j = 0; j < PT; ++j) nw[j] = w_s[pos[j]];
    __syncthreads();  // B4
    {
      float4 a, b;
      a.x = nw[0]; a.y = nw[1]; a.z = nw[2]; a.w = nw[3];
      b.x = nw[4]; b.y = nw[5]; b.z = nw[6]; b.w = nw[7];
      *(float4*)(w_s + kbase) = a;
      *(float4*)(w_s + kbase + 4) = b;
    }
#pragma unroll
    for (int j = 0; j < PT; ++j) wv[j] = nw[j];
    // No barrier here: next access to w_s (gathers) is after next B3.
  }

  if (tid == 0) out[0] = acc;
}

// ---------------------------------------------------------------------------
extern "C" void kernel_launch(void* const* d_in, const int* in_sizes, int n_in,
                              void* d_out, int out_size, void* d_ws, size_t ws_size,
                              hipStream_t stream) {
  const float* x = (const float*)d_in[0];   // [T]
  const float* w0 = (const float*)d_in[1];  // [K]
  const float* z = (const float*)d_in[2];   // [K,T]
  const float* u = (const float*)d_in[3];   // [T,K]
  float* out = (float*)d_out;

  const size_t zbytes = (size_t)KP * TSTEPS * sizeof(float);
  const size_t shmem =
      (size_t)(KP + CDF_PAD + TSTEPS + NWAVES + NBUCK) * sizeof(float);

  if (ws_size >= zbytes) {
    float* zT = (float*)d_ws;
    transpose_k<<<dim3(TSTEPS / 32, KP / 32), dim3(32, 8), 0, stream>>>(z, zT);
    smc_scan<true><<<1, BLOCK, shmem, stream>>>(x, w0, zT, u, out);
  } else {
    smc_scan<false><<<1, BLOCK, shmem, stream>>>(x, w0, z, u, out);
  }
}

// Round 4
// 26767.737 us; speedup vs baseline: 3.6447x; 1.2632x over previous
//
#include <hip/hip_runtime.h>
#include <math.h>

#define KP 8192
#define TSTEPS 4096
#define BLOCK 1024
#define PT 8                 // particles per thread = KP/BLOCK
#define NWAVES (BLOCK / 64)  // 16
#define NBUCK 8192           // bucket table size (avg occupancy 1)

// Swizzle for the CDF array: spreads per-thread stride-8 scalar writes across
// banks (9t mod 32, gcd(9,32)=1). Probes are random-addressed -> no extra term.
#define SW2(i) ((i) + ((i) >> 3))
#define CDF_PAD 9216  // SW2(8191) = 9214

// ---------------------------------------------------------------------------
// Transpose z [KP][TSTEPS] -> zT [TSTEPS][KP].
// ---------------------------------------------------------------------------
__global__ void transpose_k(const float* __restrict__ in, float* __restrict__ out) {
  __shared__ float tile[32][33];
  const int c0 = blockIdx.x * 32;
  const int r0 = blockIdx.y * 32;
  const int tx = threadIdx.x;
  const int ty = threadIdx.y;
#pragma unroll
  for (int i = 0; i < 32; i += 8)
    tile[ty + i][tx] = in[(size_t)(r0 + ty + i) * TSTEPS + c0 + tx];
  __syncthreads();
#pragma unroll
  for (int i = 0; i < 32; i += 8)
    out[(size_t)(c0 + ty + i) * KP + r0 + tx] = tile[tx][ty + i];
}

// ---------------------------------------------------------------------------
// Persistent single-workgroup SMC scan.
// Per step: exp-weights -> hierarchical prefix sum -> cdf + bucket table
// (lower bound per bucket, exact telescoping cover) -> in-bucket branchless
// binary search (worst lane = log2(bucket size)) -> gather.
// ---------------------------------------------------------------------------
template <bool ZTRANS>
__global__ __launch_bounds__(BLOCK) void smc_scan(const float* __restrict__ x,
                                                  const float* __restrict__ w0,
                                                  const float* __restrict__ zsrc,
                                                  const float* __restrict__ u,
                                                  float* __restrict__ out) {
  extern __shared__ float sm[];
  float* w_s = sm;                  // KP: particle pool (linear)
  float* cdf_s = sm + KP;           // CDF_PAD: swizzled unnormalized CDF
  float* red = cdf_s + CDF_PAD;     // NWAVES: wave totals
  int* L_s = (int*)(red + NWAVES);  // NBUCK+1: bucket -> lower_bound index

  const int tid = threadIdx.x;
  const int lane = tid & 63;
  const int wid = tid >> 6;
  const int kbase = tid * PT;
  const int wbase = SW2(kbase);  // swizzle affine within aligned 8-run

  for (int i = tid; i < KP; i += BLOCK) w_s[i] = w0[i];
  // L_s[0] stays 0 forever (fill writes start at b>=1); sentinel at NBUCK.
  for (int i = tid; i < NBUCK; i += BLOCK) L_s[i] = 0;
  if (tid == 0) L_s[NBUCK] = KP - 1;

  // Particles live in registers; w_s mirrors them for cross-thread gathers.
  float wv[PT];
  {
    float4 a = *(const float4*)(w0 + kbase);
    float4 b = *(const float4*)(w0 + kbase + 4);
    wv[0] = a.x; wv[1] = a.y; wv[2] = a.z; wv[3] = a.w;
    wv[4] = b.x; wv[5] = b.y; wv[6] = b.z; wv[7] = b.w;
  }
  __syncthreads();

  // One-step-ahead prefetch registers (z row, u row, x scalar).
  float zn[PT], un[PT];
  float xt_next = x[0];
  if (ZTRANS) {
    float4 a = *(const float4*)(zsrc + kbase);
    float4 b = *(const float4*)(zsrc + kbase + 4);
    zn[0] = a.x; zn[1] = a.y; zn[2] = a.z; zn[3] = a.w;
    zn[4] = b.x; zn[5] = b.y; zn[6] = b.z; zn[7] = b.w;
  } else {
#pragma unroll
    for (int j = 0; j < PT; ++j) zn[j] = zsrc[(size_t)(kbase + j) * TSTEPS];
  }
  {
    float4 a = *(const float4*)(u + kbase);
    float4 b = *(const float4*)(u + kbase + 4);
    un[0] = a.x; un[1] = a.y; un[2] = a.z; un[3] = a.w;
    un[4] = b.x; un[5] = b.y; un[6] = b.z; un[7] = b.w;
  }

  float acc = 0.f;

  for (int t = 0; t < TSTEPS; ++t) {
    float zv[PT], uv[PT];
#pragma unroll
    for (int j = 0; j < PT; ++j) { zv[j] = zn[j]; uv[j] = un[j]; }
    const float xt = xt_next;

    if (t + 1 < TSTEPS) {
      xt_next = x[t + 1];  // uniform scalar load, off critical path
      if (ZTRANS) {
        float4 a = *(const float4*)(zsrc + (size_t)(t + 1) * KP + kbase);
        float4 b = *(const float4*)(zsrc + (size_t)(t + 1) * KP + kbase + 4);
        zn[0] = a.x; zn[1] = a.y; zn[2] = a.z; zn[3] = a.w;
        zn[4] = b.x; zn[5] = b.y; zn[6] = b.z; zn[7] = b.w;
      } else {
#pragma unroll
        for (int j = 0; j < PT; ++j)
          zn[j] = zsrc[(size_t)(kbase + j) * TSTEPS + t + 1];
      }
      float4 a = *(const float4*)(u + (size_t)(t + 1) * KP + kbase);
      float4 b = *(const float4*)(u + (size_t)(t + 1) * KP + kbase + 4);
      un[0] = a.x; un[1] = a.y; un[2] = a.z; un[3] = a.w;
      un[4] = b.x; un[5] = b.y; un[6] = b.z; un[7] = b.w;
    }

    // ---- A: shifted weights, exp (no max-sub; fp32 range suffices since w
    // is always a permutation of w0), thread-local inclusive scan.
    float s[PT];
    float run = 0.f;
#pragma unroll
    for (int j = 0; j < PT; ++j) {
      float d = zv[j] - wv[j];
      float lw = fmaf(xt, zv[j], -0.5f * d * d);
      run += __expf(lw);
      s[j] = run;
    }
    // Wave inclusive scan of per-thread totals.
    float wincl = run;
#pragma unroll
    for (int d = 1; d < 64; d <<= 1) {
      float n = __shfl_up(wincl, d);
      if (lane >= d) wincl += n;
    }
    if (lane == 63) red[wid] = wincl;
    const float wexcl = wincl - run;
    __syncthreads();  // B1

    // ---- B: every wave redundantly scans the 16 wave totals.
    float v = red[lane & 15];
#pragma unroll
    for (int d = 1; d < 16; d <<= 1) {
      float n = __shfl_up(v, d, 16);
      if ((lane & 15) >= d) v += n;
    }
    const float wpre = wid ? __shfl(v, wid - 1, 16) : 0.f;
    const float total = __shfl(v, 15, 16);
    const float base = wpre + wexcl;
    const float nbOverT = (float)NBUCK / total;

    // ---- C1: cdf values (stored values = single source of truth).
    float cv[PT];
#pragma unroll
    for (int j = 0; j < PT; ++j) {
      cv[j] = base + s[j];
      cdf_s[wbase + j] = cv[j];
    }
    __syncthreads();  // B2

    // ---- C2: bucket table. Particle i covers buckets
    // (floor(c_{i-1}*k), floor(c_i*k)]; telescoping on stored values ->
    // every bucket in [1, NBUCK-1] written exactly once.
    {
      const float cprev = (tid == 0) ? 0.f : cdf_s[SW2(kbase - 1)];
      int flo = (int)(cprev * nbOverT);
#pragma unroll
      for (int j = 0; j < PT; ++j) {
        int fhi = (int)(cv[j] * nbOverT);
        if (fhi > NBUCK - 1) fhi = NBUCK - 1;
        if (kbase + j == KP - 1) fhi = NBUCK - 1;  // cover top buckets
        for (int b = flo + 1; b <= fhi; ++b) L_s[b] = kbase + j;
        flo = fhi;
      }
    }
    if (tid == 0)
      acc += __logf(total) - 9.0109133472792886f   // log(K)
             - 0.5f * (1.8378770664093453f + xt * xt);
    __syncthreads();  // B3

    // ---- D: bucketed branchless binary search.
    // i0 = L[b] <= answer <= i1 = L[b+1] (both proven via monotone FP mul).
    // Self-freezing: at len==0, lo is the answer, cdf[lo] >= tg -> no advance.
    int lo[PT], len[PT];
    float tg[PT];
    int anylen = 0;
#pragma unroll
    for (int j = 0; j < PT; ++j) {
      tg[j] = uv[j] * total;
      int b = (int)(tg[j] * nbOverT);
      if (b > NBUCK - 1) b = NBUCK - 1;
      const int i0 = L_s[b];
      const int i1 = L_s[b + 1];  // sentinel covers b = NBUCK-1
      lo[j] = i0;
      len[j] = i1 - i0;
      anylen |= len[j];
    }
    while (anylen) {  // parallel rounds; wave cost = max_j ceil(log2(len+1))
      anylen = 0;
#pragma unroll
      for (int j = 0; j < PT; ++j) {
        const int half = len[j] >> 1;
        const float c = cdf_s[SW2(lo[j] + half)];
        const bool adv = (c < tg[j]);
        lo[j] = adv ? lo[j] + half + 1 : lo[j];
        len[j] = adv ? len[j] - half - 1 : half;
        anylen |= len[j];
      }
    }

    // ---- E: gather, publish, keep own slice in registers.
    float nw[PT];
#pragma unroll
    for (int j = 0; j < PT; ++j) nw[j] = w_s[lo[j]];
    __syncthreads();  // B4
    {
      float4 a, b;
      a.x = nw[0]; a.y = nw[1]; a.z = nw[2]; a.w = nw[3];
      b.x = nw[4]; b.y = nw[5]; b.z = nw[6]; b.w = nw[7];
      *(float4*)(w_s + kbase) = a;
      *(float4*)(w_s + kbase + 4) = b;
    }
#pragma unroll
    for (int j = 0; j < PT; ++j) wv[j] = nw[j];
    // No barrier needed here: w_s is next read in E after next B3.
  }

  if (tid == 0) out[0] = acc;
}

// ---------------------------------------------------------------------------
extern "C" void kernel_launch(void* const* d_in, const int* in_sizes, int n_in,
                              void* d_out, int out_size, void* d_ws, size_t ws_size,
                              hipStream_t stream) {
  const float* x = (const float*)d_in[0];   // [T]
  const float* w0 = (const float*)d_in[1];  // [K]
  const float* z = (const float*)d_in[2];   // [K,T]
  const float* u = (const float*)d_in[3];   // [T,K]
  float* out = (float*)d_out;

  const size_t zbytes = (size_t)KP * TSTEPS * sizeof(float);
  const size_t shmem =
      (size_t)(KP + CDF_PAD + NWAVES + NBUCK + 1) * sizeof(float);

  if (ws_size >= zbytes) {
    float* zT = (float*)d_ws;
    transpose_k<<<dim3(TSTEPS / 32, KP / 32), dim3(32, 8), 0, stream>>>(z, zT);
    smc_scan<true><<<1, BLOCK, shmem, stream>>>(x, w0, zT, u, out);
  } else {
    smc_scan<false><<<1, BLOCK, shmem, stream>>>(x, w0, z, u, out);
  }
}

// Round 5
// 20672.772 us; speedup vs baseline: 4.7193x; 1.2948x over previous
//
#include <hip/hip_runtime.h>
#include <math.h>

#define KP 8192
#define TSTEPS 4096
#define BLOCK 1024
#define PT 8                 // particles per thread
#define NWAVES 16
#define NBUCK 8192           // bucket table (avg occupancy 1)

// Swizzle: spreads per-thread stride-8 scalar cdf writes across banks (9t mod 32).
#define SW2(i) ((i) + ((i) >> 3))
#define CDF_PAD 9216  // SW2(8191) = 9214

// ---------------- DPP wave-scan helpers (no LDS pipe, pure VALU) ----------------
template <int CTRL, int RM>
__device__ __forceinline__ float dpp_add_f(float x) {
  int s = __builtin_amdgcn_update_dpp(0, __float_as_int(x), CTRL, RM, 0xF, false);
  return x + __int_as_float(s);
}
template <int CTRL, int RM>
__device__ __forceinline__ int dpp_max_i(int x) {
  int s = __builtin_amdgcn_update_dpp(0, x, CTRL, RM, 0xF, false);
  return x > s ? x : s;
}
// Inclusive wave64 scans: row_shr 1/2/4/8 within rows of 16, then bcast15->rows{1,3},
// bcast31->rows{2,3}. Identity (old=0) is correct for add and for max over values>=0.
__device__ __forceinline__ float wscan64_add(float x) {
  x = dpp_add_f<0x111, 0xF>(x); x = dpp_add_f<0x112, 0xF>(x);
  x = dpp_add_f<0x114, 0xF>(x); x = dpp_add_f<0x118, 0xF>(x);
  x = dpp_add_f<0x142, 0xA>(x); x = dpp_add_f<0x143, 0xC>(x);
  return x;
}
__device__ __forceinline__ int wscan64_max(int x) {
  x = dpp_max_i<0x111, 0xF>(x); x = dpp_max_i<0x112, 0xF>(x);
  x = dpp_max_i<0x114, 0xF>(x); x = dpp_max_i<0x118, 0xF>(x);
  x = dpp_max_i<0x142, 0xA>(x); x = dpp_max_i<0x143, 0xC>(x);
  return x;
}
// 16-wide scan replicated in every row (input replicated via red[lane&15]).
__device__ __forceinline__ float rscan16_add(float x) {
  x = dpp_add_f<0x111, 0xF>(x); x = dpp_add_f<0x112, 0xF>(x);
  x = dpp_add_f<0x114, 0xF>(x); x = dpp_add_f<0x118, 0xF>(x);
  return x;
}
__device__ __forceinline__ int rscan16_max(int x) {
  x = dpp_max_i<0x111, 0xF>(x); x = dpp_max_i<0x112, 0xF>(x);
  x = dpp_max_i<0x114, 0xF>(x); x = dpp_max_i<0x118, 0xF>(x);
  return x;
}
__device__ __forceinline__ float readlane_f(float v, int l) {
  return __int_as_float(__builtin_amdgcn_readlane(__float_as_int(v), l));
}

// ---------------------------------------------------------------------------
// Transpose z [KP][TSTEPS] -> zT [TSTEPS][KP].
// ---------------------------------------------------------------------------
__global__ void transpose_k(const float* __restrict__ in, float* __restrict__ out) {
  __shared__ float tile[32][33];
  const int c0 = blockIdx.x * 32;
  const int r0 = blockIdx.y * 32;
  const int tx = threadIdx.x;
  const int ty = threadIdx.y;
#pragma unroll
  for (int i = 0; i < 32; i += 8)
    tile[ty + i][tx] = in[(size_t)(r0 + ty + i) * TSTEPS + c0 + tx];
  __syncthreads();
#pragma unroll
  for (int i = 0; i < 32; i += 8)
    out[(size_t)(c0 + ty + i) * KP + r0 + tx] = tile[tx][ty + i];
}

// ---------------------------------------------------------------------------
// Persistent single-workgroup SMC scan. 5 barriers/step; all phases have
// deterministic (data-independent) instruction counts.
// ---------------------------------------------------------------------------
template <bool ZTRANS>
__global__ __launch_bounds__(BLOCK) void smc_scan(const float* __restrict__ x,
                                                  const float* __restrict__ w0,
                                                  const float* __restrict__ zsrc,
                                                  const float* __restrict__ u,
                                                  float* __restrict__ out) {
  extern __shared__ float sm[];
  float* wbufA = sm;                     // KP: particle pool, buffer A
  float* wbufB = sm + KP;                // KP: particle pool, buffer B
  float* cdf_s = sm + 2 * KP;            // CDF_PAD: swizzled unnormalized CDF
  float* red   = cdf_s + CDF_PAD;        // NWAVES: float wave totals
  int*   redi  = (int*)(red + NWAVES);   // NWAVES: int wave maxes
  int*   bcI   = redi + NWAVES;          // 4: broadcast (fhiLast)
  int*   L_s   = bcI + 4;                // NBUCK+1: bucket -> lower_bound idx

  const int tid = threadIdx.x;
  const int lane = tid & 63;
  const int wid = tid >> 6;
  const int kbase = tid * PT;        // particle base; == bucket base (NBUCK==KP)
  const int wbase = SW2(kbase);

  float* wcur = wbufA;
  float* wnxt = wbufB;

  for (int i = tid; i < NBUCK; i += BLOCK) L_s[i] = 0;
  if (tid == 0) L_s[NBUCK] = KP - 1;  // sentinel, never cleared

  float wv[PT];
  {
    float4 a = *(const float4*)(w0 + kbase);
    float4 b = *(const float4*)(w0 + kbase + 4);
    wv[0] = a.x; wv[1] = a.y; wv[2] = a.z; wv[3] = a.w;
    wv[4] = b.x; wv[5] = b.y; wv[6] = b.z; wv[7] = b.w;
    *(float4*)(wcur + kbase) = a;
    *(float4*)(wcur + kbase + 4) = b;
  }
  __syncthreads();

  // One-step-ahead prefetch registers.
  float zn[PT], un[PT];
  float xt_next = x[0];
  if (ZTRANS) {
    float4 a = *(const float4*)(zsrc + kbase);
    float4 b = *(const float4*)(zsrc + kbase + 4);
    zn[0] = a.x; zn[1] = a.y; zn[2] = a.z; zn[3] = a.w;
    zn[4] = b.x; zn[5] = b.y; zn[6] = b.z; zn[7] = b.w;
  } else {
#pragma unroll
    for (int j = 0; j < PT; ++j) zn[j] = zsrc[(size_t)(kbase + j) * TSTEPS];
  }
  {
    float4 a = *(const float4*)(u + kbase);
    float4 b = *(const float4*)(u + kbase + 4);
    un[0] = a.x; un[1] = a.y; un[2] = a.z; un[3] = a.w;
    un[4] = b.x; un[5] = b.y; un[6] = b.z; un[7] = b.w;
  }

  float acc = 0.f;

  for (int t = 0; t < TSTEPS; ++t) {
    float zv[PT], uv[PT];
#pragma unroll
    for (int j = 0; j < PT; ++j) { zv[j] = zn[j]; uv[j] = un[j]; }
    const float xt = xt_next;

    if (t + 1 < TSTEPS) {
      xt_next = x[t + 1];
      if (ZTRANS) {
        float4 a = *(const float4*)(zsrc + (size_t)(t + 1) * KP + kbase);
        float4 b = *(const float4*)(zsrc + (size_t)(t + 1) * KP + kbase + 4);
        zn[0] = a.x; zn[1] = a.y; zn[2] = a.z; zn[3] = a.w;
        zn[4] = b.x; zn[5] = b.y; zn[6] = b.z; zn[7] = b.w;
      } else {
#pragma unroll
        for (int j = 0; j < PT; ++j)
          zn[j] = zsrc[(size_t)(kbase + j) * TSTEPS + t + 1];
      }
      float4 a = *(const float4*)(u + (size_t)(t + 1) * KP + kbase);
      float4 b = *(const float4*)(u + (size_t)(t + 1) * KP + kbase + 4);
      un[0] = a.x; un[1] = a.y; un[2] = a.z; un[3] = a.w;
      un[4] = b.x; un[5] = b.y; un[6] = b.z; un[7] = b.w;
    }

    // ---- A: shifted weights, exp (fp32 range suffices: w is a permutation
    // of w0), thread-local inclusive scan, DPP wave scan.
    float s[PT];
    float run = 0.f;
#pragma unroll
    for (int j = 0; j < PT; ++j) {
      float d = zv[j] - wv[j];
      float lw = fmaf(xt, zv[j], -0.5f * d * d);
      run += __expf(lw);
      s[j] = run;
    }
    const float wincl = wscan64_add(run);
    const float wexcl = wincl - run;
    if (lane == 63) red[wid] = wincl;
    __syncthreads();  // B1  (also: prev-step D/E LDS reads all done)

    // ---- B: cross-wave float scan (replicated per row, DPP).
    float v16 = rscan16_add(red[lane & 15]);
    const float total = readlane_f(v16, 15);
    const float wpre = wid ? readlane_f(v16, wid - 1) : 0.f;
    const float base = wpre + wexcl;
    const float nbOverT = (float)NBUCK / total;

    // ---- C1: cdf writes (conflict-free 9t mod 32), fhiLast bcast, clear L.
    float cv[PT];
#pragma unroll
    for (int j = 0; j < PT; ++j) {
      cv[j] = base + s[j];
      cdf_s[wbase + j] = cv[j];
    }
    if (tid == BLOCK - 1) bcI[0] = (int)(cv[PT - 1] * nbOverT);
    {
      int4 z4; z4.x = z4.y = z4.z = z4.w = 0;
      *(int4*)(L_s + kbase) = z4;
      *(int4*)(L_s + kbase + 4) = z4;
    }
    if (tid == 0)
      acc += __logf(total) - 9.0109133472792886f   // log(K)
             - 0.5f * (1.8378770664093453f + xt * xt);
    __syncthreads();  // B2

    // ---- C2a: scatter. Covering particle i writes L[flo_i+1] = i (race-free:
    // writers have strictly increasing flo in the clamped telescoping chain).
    {
      const float cprev = tid ? cdf_s[SW2(kbase - 1)] : 0.f;
      int flo = (int)(cprev * nbOverT);
#pragma unroll
      for (int j = 0; j < PT; ++j) {
        int fhi = (int)(cv[j] * nbOverT);
        if (fhi > NBUCK - 1) fhi = NBUCK - 1;
        if (fhi > flo) L_s[flo + 1] = kbase + j;
        flo = fhi;
      }
    }
    __syncthreads();  // B2b

    // ---- C2b: local + wave max-scan over scattered L.
    int4 ra = *(const int4*)(L_s + kbase);
    int4 rb = *(const int4*)(L_s + kbase + 4);
    int c0 = ra.x;
    int c1 = max(c0, ra.y);
    int c2 = max(c1, ra.z);
    int c3 = max(c2, ra.w);
    int c4 = max(c3, rb.x);
    int c5 = max(c4, rb.y);
    int c6 = max(c5, rb.z);
    int c7 = max(c6, rb.w);
    const int mincl = wscan64_max(c7);
    int mexcl = __shfl_up(mincl, 1);
    if (lane == 0) mexcl = 0;
    if (lane == 63) redi[wid] = mincl;
    __syncthreads();  // B2c

    // ---- C2c: cross-wave max, finalize L in place + top-fix (b > fhiLast ->
    // KP-1: no particle's cdf reaches those buckets; proofs as before).
    {
      int mv = rscan16_max(redi[lane & 15]);
      const int crosspre = wid ? __builtin_amdgcn_readlane(mv, wid - 1) : 0;
      const int fhiLast = bcI[0];
      int m = max(crosspre, mexcl);
      int4 oa, ob;
      m = max(m, ra.x); oa.x = (kbase + 0 > fhiLast) ? (KP - 1) : m;
      m = max(m, ra.y); oa.y = (kbase + 1 > fhiLast) ? (KP - 1) : m;
      m = max(m, ra.z); oa.z = (kbase + 2 > fhiLast) ? (KP - 1) : m;
      m = max(m, ra.w); oa.w = (kbase + 3 > fhiLast) ? (KP - 1) : m;
      m = max(m, rb.x); ob.x = (kbase + 4 > fhiLast) ? (KP - 1) : m;
      m = max(m, rb.y); ob.y = (kbase + 5 > fhiLast) ? (KP - 1) : m;
      m = max(m, rb.z); ob.z = (kbase + 6 > fhiLast) ? (KP - 1) : m;
      m = max(m, rb.w); ob.w = (kbase + 7 > fhiLast) ? (KP - 1) : m;
      *(int4*)(L_s + kbase) = oa;
      *(int4*)(L_s + kbase + 4) = ob;
    }
    __syncthreads();  // B3

    // ---- D: bucketed branchless binary search (window [L[b], L[b+1]]).
    int lo[PT], len[PT];
    float tg[PT];
    int anylen = 0;
#pragma unroll
    for (int j = 0; j < PT; ++j) {
      tg[j] = uv[j] * total;
      int b = (int)(tg[j] * nbOverT);
      if (b > NBUCK - 1) b = NBUCK - 1;
      const int i0 = L_s[b];
      const int i1 = L_s[b + 1];
      lo[j] = i0;
      len[j] = i1 - i0;
      anylen |= len[j];
    }
    while (anylen) {  // parallel rounds; wave cost = max_j ceil(log2(len+1))
      anylen = 0;
#pragma unroll
      for (int j = 0; j < PT; ++j) {
        const int half = len[j] >> 1;
        const float c = cdf_s[SW2(lo[j] + half)];
        const bool adv = (c < tg[j]);
        lo[j] = adv ? lo[j] + half + 1 : lo[j];
        len[j] = adv ? len[j] - half - 1 : half;
        anylen |= len[j];
      }
    }

    // ---- E: gather from wcur, write to wnxt (double buffer: no barrier).
    float nw[PT];
#pragma unroll
    for (int j = 0; j < PT; ++j) nw[j] = wcur[lo[j]];
    {
      float4 a, b;
      a.x = nw[0]; a.y = nw[1]; a.z = nw[2]; a.w = nw[3];
      b.x = nw[4]; b.y = nw[5]; b.z = nw[6]; b.w = nw[7];
      *(float4*)(wnxt + kbase) = a;
      *(float4*)(wnxt + kbase + 4) = b;
    }
#pragma unroll
    for (int j = 0; j < PT; ++j) wv[j] = nw[j];
    float* tmp = wcur; wcur = wnxt; wnxt = tmp;
  }

  if (tid == 0) out[0] = acc;
}

// ---------------------------------------------------------------------------
extern "C" void kernel_launch(void* const* d_in, const int* in_sizes, int n_in,
                              void* d_out, int out_size, void* d_ws, size_t ws_size,
                              hipStream_t stream) {
  const float* x = (const float*)d_in[0];   // [T]
  const float* w0 = (const float*)d_in[1];  // [K]
  const float* z = (const float*)d_in[2];   // [K,T]
  const float* u = (const float*)d_in[3];   // [T,K]
  float* out = (float*)d_out;

  const size_t zbytes = (size_t)KP * TSTEPS * sizeof(float);
  const size_t shmem =
      (size_t)(2 * KP + CDF_PAD + NWAVES + NWAVES + 4 + NBUCK + 1) * sizeof(float);

  if (ws_size >= zbytes) {
    float* zT = (float*)d_ws;
    transpose_k<<<dim3(TSTEPS / 32, KP / 32), dim3(32, 8), 0, stream>>>(z, zT);
    smc_scan<true><<<1, BLOCK, shmem, stream>>>(x, w0, zT, u, out);
  } else {
    smc_scan<false><<<1, BLOCK, shmem, stream>>>(x, w0, z, u, out);
  }
}